// Round 1
// baseline (459.812 us; speedup 1.0000x reference)
//
#include <hip/hip_runtime.h>
#include <hip/hip_bf16.h>
#include <hip/hip_fp16.h>

typedef __attribute__((ext_vector_type(8))) short short8;
typedef __attribute__((ext_vector_type(4))) float f32x4;

#define MFMA16(a, b, c) __builtin_amdgcn_mfma_f32_16x16x32_bf16(a, b, c, 0, 0, 0)

__device__ __forceinline__ short f2bf(float f) {
    unsigned u = __float_as_uint(f);
    unsigned r = (u + 0x7fffu + ((u >> 16) & 1u)) >> 16;
    return (short)r;
}
__device__ __forceinline__ float bf2f(short s) {
    return __uint_as_float(((unsigned)(unsigned short)s) << 16);
}

// ---------------- tiny prep kernels ----------------

__global__ __launch_bounds__(256) void k_wcvt(const float* qkv_w, const float* proj_w,
                                              short* wq, short* wp) {
    int i = blockIdx.x * 256 + threadIdx.x;
    if (i < 576 * 192) wq[i] = f2bf(qkv_w[i]);
    else {
        int j = i - 576 * 192;
        if (j < 192 * 192) wp[j] = f2bf(proj_w[j]);
    }
}

// cpb MLP: 507 entries, 3 -> 512 relu -> 6
__global__ __launch_bounds__(64) void k_tbl(const float* tab, const float* w1, const float* b1,
                                            const float* w2, float* tbl) {
    int e = blockIdx.x;
    int t = threadIdx.x;
    float c0 = tab[e * 3 + 0], c1 = tab[e * 3 + 1], c2 = tab[e * 3 + 2];
    float acc[6] = {0.f, 0.f, 0.f, 0.f, 0.f, 0.f};
    for (int u = t; u < 512; u += 64) {
        float hv = c0 * w1[u * 3 + 0] + c1 * w1[u * 3 + 1] + c2 * w1[u * 3 + 2] + b1[u];
        hv = fmaxf(hv, 0.f);
        #pragma unroll
        for (int hh = 0; hh < 6; ++hh) acc[hh] += hv * w2[hh * 512 + u];
    }
    #pragma unroll
    for (int hh = 0; hh < 6; ++hh) {
        float v = acc[hh];
        for (int off = 32; off > 0; off >>= 1) v += __shfl_xor(v, off, 64);
        if (t == 0) tbl[e * 6 + hh] = v;
    }
}

// bm[w][h][r][m] = 16*sigmoid(tbl[rpi[r][m]][h]) + mask[w][r][m]   (fp16)
__global__ __launch_bounds__(256) void k_bm(const float* tbl, const int* rpi, const float* mask,
                                            __half* bm) {
    int i = blockIdx.x * 256 + threadIdx.x;
    if (i >= 64 * 6 * 98 * 98) return;
    int m = i % 98;
    int r = (i / 98) % 98;
    int hh = (i / 9604) % 6;
    int w = i / 57624;
    float t = tbl[rpi[r * 98 + m] * 6 + hh];
    float v = 16.f / (1.f + expf(-t)) + mask[(w * 98 + r) * 98 + m];
    bm[i] = __float2half(v);
}

// ---------------- qkv GEMM ----------------
// C[200704, 576] = x[200704,192] @ qkv_w^T ; block = 64 rows, loops all 9 col-tiles.
// Epilogue scatters bf16 into qkvo[b][which][h][n][d].
__global__ __launch_bounds__(256) void k_qkv(const float* x, const short* wq, const float* qkv_b,
                                             short* qkvo) {
    __shared__ short As[64 * 200];
    __shared__ short Bs[64 * 200];
    int tid = threadIdx.x;
    int mtile = blockIdx.x;
    for (int c = tid; c < 1536; c += 256) {
        int r = c / 24, k0 = (c % 24) * 8;
        const float* src = x + (mtile * 64 + r) * 192 + k0;
        float4 f0 = *(const float4*)src;
        float4 f1 = *(const float4*)(src + 4);
        short8 v;
        v[0] = f2bf(f0.x); v[1] = f2bf(f0.y); v[2] = f2bf(f0.z); v[3] = f2bf(f0.w);
        v[4] = f2bf(f1.x); v[5] = f2bf(f1.y); v[6] = f2bf(f1.z); v[7] = f2bf(f1.w);
        *(short8*)&As[r * 200 + k0] = v;
    }
    int lane = tid & 63, wv = tid >> 6;
    int l16 = lane & 15, q4 = lane >> 4;
    int wr = (wv >> 1) * 32, wc = (wv & 1) * 32;
    for (int nt = 0; nt < 9; ++nt) {
        __syncthreads();
        for (int c = tid; c < 1536; c += 256) {
            int r = c / 24, k0 = (c % 24) * 8;
            *(short8*)&Bs[r * 200 + k0] = *(const short8*)(wq + (nt * 64 + r) * 192 + k0);
        }
        __syncthreads();
        f32x4 acc[2][2] = {};
        #pragma unroll
        for (int ks = 0; ks < 6; ++ks) {
            int ko = ks * 32 + q4 * 8;
            short8 a0 = *(const short8*)&As[(wr + l16) * 200 + ko];
            short8 a1 = *(const short8*)&As[(wr + 16 + l16) * 200 + ko];
            short8 b0 = *(const short8*)&Bs[(wc + l16) * 200 + ko];
            short8 b1 = *(const short8*)&Bs[(wc + 16 + l16) * 200 + ko];
            acc[0][0] = MFMA16(a0, b0, acc[0][0]);
            acc[0][1] = MFMA16(a0, b1, acc[0][1]);
            acc[1][0] = MFMA16(a1, b0, acc[1][0]);
            acc[1][1] = MFMA16(a1, b1, acc[1][1]);
        }
        #pragma unroll
        for (int mf = 0; mf < 2; ++mf)
            #pragma unroll
            for (int nf = 0; nf < 2; ++nf) {
                int colL = wc + nf * 16 + l16;
                int cg = nt * 64 + colL;
                int which = cg / 192, rem = cg % 192;
                int hh = rem >> 5, d = rem & 31;
                float bia = qkv_b[cg];
                int row0 = wr + mf * 16 + q4 * 4;
                #pragma unroll
                for (int i = 0; i < 4; ++i) {
                    int m = mtile * 64 + row0 + i;
                    int b = m / 98, n = m - b * 98;
                    qkvo[((b * 3 + which) * 6 + hh) * 3136 + n * 32 + d] =
                        f2bf(acc[mf][nf][i] + bia);
                }
            }
    }
}

// ---------------- fused attention per (b, h) ----------------
#define VT_IDX(d, m) ((d) * 128 + ((((m) >> 3) ^ ((d) & 7)) << 3) + ((m) & 7))
#define P_IDX(r, cl) ((r) * 128 + ((((cl) >> 3) ^ ((r) & 7)) << 3) + ((cl) & 7))

__global__ __launch_bounds__(448) void k_attn(const short* qkv, const __half* bm,
                                              const float* logit_scale, short* tmp) {
    __shared__ short qn[112 * 32];
    __shared__ short kn[112 * 32];
    __shared__ short vT[32 * 128];
    __shared__ short Psh[7 * 16 * 128];
    int tid = threadIdx.x;
    int bx = blockIdx.x;
    int b = bx / 6, hh = bx - b * 6;
    int wdw = b & 63;
    int lane = tid & 63, wv = tid >> 6;
    int l16 = lane & 15, q4 = lane >> 4;
    float scale = expf(fminf(logit_scale[hh], 4.60517018598809136f));
    size_t qb = ((size_t)(b * 3 + 0) * 6 + hh) * 3136;
    size_t kb = ((size_t)(b * 3 + 1) * 6 + hh) * 3136;
    size_t vb = ((size_t)(b * 3 + 2) * 6 + hh) * 3136;

    // zero pads: qn/kn rows 98..111
    if (tid < 112) {
        int ten = tid / 56, cc0 = tid % 56;
        int r = 98 + cc0 / 4, k0 = (cc0 & 3) * 8;
        short8 z = {0, 0, 0, 0, 0, 0, 0, 0};
        *(short8*)&(ten ? kn : qn)[r * 32 + k0] = z;
    }
    // vT pad: m in [98,128)
    for (int c = tid; c < 960; c += 448) {
        int d = c / 30, m = 98 + c % 30;
        vT[VT_IDX(d, m)] = 0;
    }
    // P pad (own wave): chunks 14,15 of each row
    {
        short* Pw = Psh + wv * 16 * 128;
        if (lane < 32) {
            int r = lane & 15, ch = 14 + (lane >> 4);
            short8 z = {0, 0, 0, 0, 0, 0, 0, 0};
            *(short8*)&Pw[r * 128 + ((ch ^ (r & 7)) << 3)] = z;
        }
    }
    // stage q,k with l2-normalize (+scale folded into q)
    if (tid < 196) {
        int ten = tid / 98, r = tid % 98;
        const short* src = qkv + (ten ? kb : qb) + r * 32;
        float f[32];
        #pragma unroll
        for (int j = 0; j < 4; ++j) {
            short8 v = *(const short8*)(src + j * 8);
            #pragma unroll
            for (int jj = 0; jj < 8; ++jj) f[j * 8 + jj] = bf2f(v[jj]);
        }
        float ss = 0.f;
        #pragma unroll
        for (int j = 0; j < 32; ++j) ss += f[j] * f[j];
        float rn = (ten ? 1.f : scale) / fmaxf(sqrtf(ss), 1e-12f);
        short* dst = (ten ? kn : qn) + r * 32;
        #pragma unroll
        for (int j = 0; j < 4; ++j) {
            short8 v;
            #pragma unroll
            for (int jj = 0; jj < 8; ++jj) v[jj] = f2bf(f[j * 8 + jj] * rn);
            *(short8*)&dst[j * 8] = v;
        }
    }
    // stage v (transposed + swizzled)
    if (tid < 392) {
        int m = tid >> 2, d0 = (tid & 3) * 8;
        short8 v = *(const short8*)(qkv + vb + m * 32 + d0);
        #pragma unroll
        for (int j = 0; j < 8; ++j) vT[VT_IDX(d0 + j, m)] = v[j];
    }
    __syncthreads();

    // QK^T : wave wv owns rows [wv*16, wv*16+16)
    f32x4 zz = {0.f, 0.f, 0.f, 0.f};
    short8 af = *(const short8*)&qn[(wv * 16 + l16) * 32 + q4 * 8];
    f32x4 cc[7];
    #pragma unroll
    for (int ct = 0; ct < 7; ++ct) {
        short8 bf = *(const short8*)&kn[(ct * 16 + l16) * 32 + q4 * 8];
        cc[ct] = MFMA16(af, bf, zz);
    }
    int r0 = wv * 16 + q4 * 4;
    const __half* bmp = bm + ((size_t)(wdw * 6 + hh)) * 9604;
    #pragma unroll
    for (int ct = 0; ct < 7; ++ct) {
        int col = ct * 16 + l16;
        #pragma unroll
        for (int i = 0; i < 4; ++i) {
            int r = r0 + i;
            float s;
            if (r < 98 && col < 98) s = cc[ct][i] + __half2float(bmp[r * 98 + col]);
            else s = -1e30f;
            cc[ct][i] = s;
        }
    }
    // softmax over the 7 col-frags (row lives in 16 lanes of this group)
    float rinv[4];
    #pragma unroll
    for (int i = 0; i < 4; ++i) {
        float mx = cc[0][i];
        #pragma unroll
        for (int ct = 1; ct < 7; ++ct) mx = fmaxf(mx, cc[ct][i]);
        for (int off = 1; off < 16; off <<= 1) mx = fmaxf(mx, __shfl_xor(mx, off, 16));
        float sm = 0.f;
        #pragma unroll
        for (int ct = 0; ct < 7; ++ct) {
            float e = __expf(cc[ct][i] - mx);
            cc[ct][i] = e;
            sm += e;
        }
        for (int off = 1; off < 16; off <<= 1) sm += __shfl_xor(sm, off, 16);
        rinv[i] = 1.f / sm;
    }
    // write P (bf16, swizzled) to own-wave LDS slice
    short* Pw = Psh + wv * 16 * 128;
    #pragma unroll
    for (int ct = 0; ct < 7; ++ct) {
        int col = ct * 16 + l16;
        #pragma unroll
        for (int i = 0; i < 4; ++i) Pw[P_IDX(q4 * 4 + i, col)] = f2bf(cc[ct][i]);
    }
    __syncthreads();
    // PV
    f32x4 o0 = {0.f, 0.f, 0.f, 0.f}, o1 = {0.f, 0.f, 0.f, 0.f};
    #pragma unroll
    for (int km = 0; km < 4; ++km) {
        int ch = km * 4 + q4;
        short8 pa = *(const short8*)&Pw[l16 * 128 + ((ch ^ (l16 & 7)) << 3)];
        short8 v0 = *(const short8*)&vT[l16 * 128 + ((ch ^ (l16 & 7)) << 3)];
        short8 v1 = *(const short8*)&vT[(16 + l16) * 128 + ((ch ^ ((16 + l16) & 7)) << 3)];
        o0 = MFMA16(pa, v0, o0);
        o1 = MFMA16(pa, v1, o1);
    }
    #pragma unroll
    for (int i = 0; i < 4; ++i) {
        int r = r0 + i;
        if (r < 98) {
            size_t obase = ((size_t)(b * 98 + r)) * 192 + hh * 32;
            tmp[obase + l16] = f2bf(o0[i] * rinv[i]);
            tmp[obase + 16 + l16] = f2bf(o1[i] * rinv[i]);
        }
    }
}

// ---------------- proj GEMM ----------------
__global__ __launch_bounds__(256) void k_proj(const short* tmp, const short* wp,
                                              const float* proj_b, float* outp) {
    __shared__ short As[64 * 200];
    __shared__ short Bs[64 * 200];
    int tid = threadIdx.x, mtile = blockIdx.x;
    for (int c = tid; c < 1536; c += 256) {
        int r = c / 24, k0 = (c % 24) * 8;
        *(short8*)&As[r * 200 + k0] =
            *(const short8*)(tmp + ((size_t)(mtile * 64 + r)) * 192 + k0);
    }
    int lane = tid & 63, wv = tid >> 6;
    int l16 = lane & 15, q4 = lane >> 4;
    int wr = (wv >> 1) * 32, wc = (wv & 1) * 32;
    for (int nt = 0; nt < 3; ++nt) {
        __syncthreads();
        for (int c = tid; c < 1536; c += 256) {
            int r = c / 24, k0 = (c % 24) * 8;
            *(short8*)&Bs[r * 200 + k0] = *(const short8*)(wp + (nt * 64 + r) * 192 + k0);
        }
        __syncthreads();
        f32x4 acc[2][2] = {};
        #pragma unroll
        for (int ks = 0; ks < 6; ++ks) {
            int ko = ks * 32 + q4 * 8;
            short8 a0 = *(const short8*)&As[(wr + l16) * 200 + ko];
            short8 a1 = *(const short8*)&As[(wr + 16 + l16) * 200 + ko];
            short8 b0 = *(const short8*)&Bs[(wc + l16) * 200 + ko];
            short8 b1 = *(const short8*)&Bs[(wc + 16 + l16) * 200 + ko];
            acc[0][0] = MFMA16(a0, b0, acc[0][0]);
            acc[0][1] = MFMA16(a0, b1, acc[0][1]);
            acc[1][0] = MFMA16(a1, b0, acc[1][0]);
            acc[1][1] = MFMA16(a1, b1, acc[1][1]);
        }
        #pragma unroll
        for (int mf = 0; mf < 2; ++mf)
            #pragma unroll
            for (int nf = 0; nf < 2; ++nf) {
                int cg = nt * 64 + wc + nf * 16 + l16;
                float bia = proj_b[cg];
                int row0 = wr + mf * 16 + q4 * 4;
                #pragma unroll
                for (int i = 0; i < 4; ++i) {
                    int m = mtile * 64 + row0 + i;
                    outp[(size_t)m * 192 + cg] = acc[mf][nf][i] + bia;
                }
            }
    }
}

extern "C" void kernel_launch(void* const* d_in, const int* in_sizes, int n_in,
                              void* d_out, int out_size, void* d_ws, size_t ws_size,
                              hipStream_t stream) {
    const float* x    = (const float*)d_in[0];
    const float* mask = (const float*)d_in[1];
    const float* qkvw = (const float*)d_in[2];
    const float* qkvb = (const float*)d_in[3];
    const float* lsc  = (const float*)d_in[4];
    const float* w1   = (const float*)d_in[5];
    const float* b1   = (const float*)d_in[6];
    const float* w2   = (const float*)d_in[7];
    const float* pw   = (const float*)d_in[8];
    const float* pb   = (const float*)d_in[9];
    const float* tab  = (const float*)d_in[10];
    const int*   rpi  = (const int*)d_in[11];

    char* ws = (char*)d_ws;
    short*  qkvo = (short*)(ws + 0);               // 231,211,008 B
    short*  tmp  = (short*)(ws + 231211008LL);     //  77,070,336 B
    short*  wq   = (short*)(ws + 308281344LL);     //     221,184 B
    short*  wp   = (short*)(ws + 308502528LL);     //      73,728 B
    float*  tbl  = (float*)(ws + 308576256LL);     //      12,288 B (padded)
    __half* bm   = (__half*)(ws + 308588544LL);    //   7,375,872 B
    float*  outp = (float*)d_out;

    k_wcvt<<<576, 256, 0, stream>>>(qkvw, pw, wq, wp);
    k_tbl<<<507, 64, 0, stream>>>(tab, w1, b1, w2, tbl);
    k_bm<<<14406, 256, 0, stream>>>(tbl, rpi, mask, bm);
    k_qkv<<<3136, 256, 0, stream>>>(x, wq, qkvb, qkvo);
    k_attn<<<12288, 448, 0, stream>>>(qkvo, bm, lsc, tmp);
    k_proj<<<3136, 256, 0, stream>>>(tmp, wp, pb, outp);
}